// Round 4
// baseline (88.313 us; speedup 1.0000x reference)
//
#include <hip/hip_runtime.h>

// out[c] = sum_i pre[idx_i][c] + dot(W[c,:], sum_i memb[idx_i]) + N*bias[c]
//
// Histogram formulation: counts[v] = multiplicity of row v (only ~39% of the
// 200k vocab rows are touched by 100k uniform draws), then one monotone
// weighted scan reads each unique row ONCE from both tables (~158 MB vs 205).
//
// R4 changes vs R3:
//  - scan loop: compact surviving (row,weight) pairs into LDS, then a
//    counted loop with #pragma unroll 4 -> 8 row loads in flight per wave
//    (the old while(ballot) loop was unrollable only 2-wide and serialized
//    on vmcnt waits)
//  - nontemporal row loads (rows are read-once; don't thrash L2/L3)
//  - finish matvec folded into the scan kernel via last-block ticket:
//    4 dispatches -> 3
//
// d_ws layout: [counts: V int32][acc: NCOPY*512 f32][done: int]

typedef float f4 __attribute__((ext_vector_type(4)));

#define NCOPY 16

__global__ __launch_bounds__(256) void hist_kernel(
    const int* __restrict__ idx, int* __restrict__ counts, int n)
{
    const int i = blockIdx.x * blockDim.x + threadIdx.x;
    if (i < n) atomicAdd(&counts[idx[i]], 1);
}

__global__ __launch_bounds__(256) void scan_finish_kernel(
    const int* __restrict__ counts,
    const float* __restrict__ memb,   // [V,256]
    const float* __restrict__ pre,    // [V,256]
    float* __restrict__ acc,          // [NCOPY][512]
    int* __restrict__ done,
    const float* __restrict__ W,      // [256,256] row-major
    const float* __restrict__ bias,
    float* __restrict__ out,          // [256]
    int vocab, float nf, int nblocks)
{
    const int lane = threadIdx.x & 63;
    const int wv   = threadIdx.x >> 6;                       // wave in block
    const int wid  = (blockIdx.x * blockDim.x + threadIdx.x) >> 6;
    const int base = wid * 64;                               // 64-row tile

    __shared__ int   sRow[4][64];
    __shared__ float sWt [4][64];

    // Load this tile's counts (coalesced) and compact survivors into LDS.
    int c = 0;
    if (base + lane < vocab) c = counts[base + lane];
    const unsigned long long mm = __ballot(c != 0);
    const int nv = __popcll(mm);
    if (c != 0) {
        const int pos = __popcll(mm & ((1ull << lane) - 1));
        sRow[wv][pos] = lane;
        sWt [wv][pos] = (float)c;
    }
    __syncthreads();

    f4 accS = {0.f, 0.f, 0.f, 0.f};
    f4 accP = {0.f, 0.f, 0.f, 0.f};

    const f4* mrow = reinterpret_cast<const f4*>(memb) + (size_t)base * 64 + lane;
    const f4* prow = reinterpret_cast<const f4*>(pre)  + (size_t)base * 64 + lane;

    // Fixed-trip loop over survivors: unroll 4 -> 8 independent 1KB row
    // loads in flight per wave. Rows are read-once -> nontemporal.
    #pragma unroll 4
    for (int j = 0; j < nv; ++j) {
        const int   k = sRow[wv][j];                          // broadcast LDS read
        const float w = sWt [wv][j];
        const f4 a = __builtin_nontemporal_load(mrow + (size_t)k * 64);
        const f4 b = __builtin_nontemporal_load(prow + (size_t)k * 64);
        accS += a * w;
        accP += b * w;
    }

    // Block reduction: lane l owns channels [4l,4l+4).
    __shared__ float sS[256];
    __shared__ float sP[256];
    sS[threadIdx.x] = 0.f;
    sP[threadIdx.x] = 0.f;
    __syncthreads();

    const int ch = lane * 4;
    atomicAdd(&sS[ch + 0], accS.x); atomicAdd(&sS[ch + 1], accS.y);
    atomicAdd(&sS[ch + 2], accS.z); atomicAdd(&sS[ch + 3], accS.w);
    atomicAdd(&sP[ch + 0], accP.x); atomicAdd(&sP[ch + 1], accP.y);
    atomicAdd(&sP[ch + 2], accP.z); atomicAdd(&sP[ch + 3], accP.w);
    __syncthreads();

    float* myacc = acc + (size_t)(blockIdx.x & (NCOPY - 1)) * 512;
    atomicAdd(&myacc[threadIdx.x],       sS[threadIdx.x]);
    atomicAdd(&myacc[256 + threadIdx.x], sP[threadIdx.x]);

    // Last-block-done ticket -> finish (combine copies + 256x256 matvec).
    __shared__ int lastFlag;
    if (threadIdx.x == 0) {
        __threadfence();
        lastFlag = (atomicAdd(done, 1) == nblocks - 1);
    }
    __syncthreads();
    if (!lastFlag) return;
    __threadfence();   // acquire: make all blocks' acc atomics visible

    const int t = threadIdx.x;
    float s_t = 0.f, p_t = 0.f;
    #pragma unroll
    for (int cp = 0; cp < NCOPY; ++cp) {
        s_t += acc[cp * 512 + t];
        p_t += acc[cp * 512 + 256 + t];
    }

    __shared__ float sVec[256];
    sVec[t] = s_t;
    __syncthreads();

    float v = 0.f;
    #pragma unroll 8
    for (int k = 0; k < 256; ++k)
        v = fmaf(W[(size_t)t * 256 + k], sVec[k], v);

    out[t] = v + p_t + nf * bias[t];
}

// Fallback (ws too small): direct strided gather into acc copies + finish.
__global__ __launch_bounds__(256) void gather_sum_kernel(
    const int* __restrict__ idx,
    const float* __restrict__ memb,
    const float* __restrict__ pre,
    float* __restrict__ acc,
    int n)
{
    const int lane = threadIdx.x & 63;
    const int wave = threadIdx.x >> 6;
    const int globalWave = blockIdx.x * 4 + wave;
    const int totalWaves = gridDim.x * 4;

    f4 accS = {0.f,0.f,0.f,0.f};
    f4 accP = {0.f,0.f,0.f,0.f};

    for (int i = globalWave; i < n; i += totalWaves) {
        const int r = idx[i];
        const f4 a = reinterpret_cast<const f4*>(memb + (size_t)r * 256)[lane];
        const f4 b = reinterpret_cast<const f4*>(pre  + (size_t)r * 256)[lane];
        accS += a; accP += b;
    }

    __shared__ float sS[256];
    __shared__ float sP[256];
    sS[threadIdx.x] = 0.f;
    sP[threadIdx.x] = 0.f;
    __syncthreads();
    const int ch = lane * 4;
    atomicAdd(&sS[ch + 0], accS.x); atomicAdd(&sS[ch + 1], accS.y);
    atomicAdd(&sS[ch + 2], accS.z); atomicAdd(&sS[ch + 3], accS.w);
    atomicAdd(&sP[ch + 0], accP.x); atomicAdd(&sP[ch + 1], accP.y);
    atomicAdd(&sP[ch + 2], accP.z); atomicAdd(&sP[ch + 3], accP.w);
    __syncthreads();
    float* myacc = acc + (size_t)(blockIdx.x & (NCOPY - 1)) * 512;
    atomicAdd(&myacc[threadIdx.x],       sS[threadIdx.x]);
    atomicAdd(&myacc[256 + threadIdx.x], sP[threadIdx.x]);
}

__global__ __launch_bounds__(256) void finish_kernel(
    const float* __restrict__ acc,
    const float* __restrict__ W,
    const float* __restrict__ bias,
    float* __restrict__ out,
    float nf)
{
    const int c = blockIdx.x;
    const int t = threadIdx.x;

    float s_t = 0.f;
    #pragma unroll
    for (int cp = 0; cp < NCOPY; ++cp) s_t += acc[cp * 512 + t];

    float v = W[(size_t)c * 256 + t] * s_t;
    for (int off = 32; off > 0; off >>= 1)
        v += __shfl_down(v, off, 64);

    __shared__ float part[4];
    if ((t & 63) == 0) part[t >> 6] = v;
    __syncthreads();

    if (t == 0) {
        float p_c = 0.f;
        #pragma unroll
        for (int cp = 0; cp < NCOPY; ++cp) p_c += acc[cp * 512 + 256 + c];
        out[c] = (part[0] + part[1] + part[2] + part[3]) + p_c + nf * bias[c];
    }
}

extern "C" void kernel_launch(void* const* d_in, const int* in_sizes, int n_in,
                              void* d_out, int out_size, void* d_ws, size_t ws_size,
                              hipStream_t stream)
{
    const int*   idx  = (const int*)d_in[0];     // medicine_it      [N]
    const float* memb = (const float*)d_in[1];   // m_embeddings     [V,256]
    const float* pre  = (const float*)d_in[2];   // pretrained_weight[V,256]
    const float* W    = (const float*)d_in[3];   // W                [256,256]
    const float* bias = (const float*)d_in[4];   // bias             [256]
    float* out = (float*)d_out;

    const int n     = in_sizes[0];
    const int vocab = in_sizes[1] / 256;

    const size_t countsBytes = (size_t)vocab * sizeof(int);
    const size_t accBytes    = (size_t)NCOPY * 512 * sizeof(float);

    if (ws_size >= countsBytes + accBytes + 64) {
        int*   counts = (int*)d_ws;
        float* acc    = (float*)((char*)d_ws + countsBytes);
        int*   done   = (int*)((char*)d_ws + countsBytes + accBytes);

        hipMemsetAsync(d_ws, 0, countsBytes + accBytes + 64, stream);

        hist_kernel<<<(n + 255) / 256, 256, 0, stream>>>(idx, counts, n);

        const int waves  = (vocab + 63) / 64;
        const int blocks = (waves + 3) / 4;
        scan_finish_kernel<<<blocks, 256, 0, stream>>>(
            counts, memb, pre, acc, done, W, bias, out, vocab, (float)n, blocks);
    } else {
        float* acc = (float*)d_ws;
        hipMemsetAsync(d_ws, 0, accBytes, stream);
        gather_sum_kernel<<<512, 256, 0, stream>>>(idx, memb, pre, acc, n);
        finish_kernel<<<256, 256, 0, stream>>>(acc, W, bias, out, (float)n);
    }
}

// Round 5
// 49.709 us; speedup vs baseline: 1.7766x; 1.7766x over previous
//
#include <hip/hip_runtime.h>

// out[c] = sum_i pre[idx_i][c] + dot(W[c,:], sum_i memb[idx_i]) + N*bias[c]
//
// Histogram formulation: counts[v] = multiplicity of row v (~39% of the 200k
// vocab rows are touched by 100k uniform draws); one monotone weighted scan
// then reads each unique row ONCE from each table (~158 MB vs ~205 MB).
//
// R5 vs R3 (R4's LDS-indirect loop + nontemporal loads regressed, reverted):
//  - table streams split across waves: even waves sum memb, odd waves sum
//    pre over the same 64-row window -> 6250 waves (~24/CU, was ~12/CU)
//  - 4 rows per while-iteration (register-only ffs/shfl deps, tail pads
//    with weight-0 duplicate of the first row -> L1 hit)
//
// d_ws layout: [counts: V int32][acc: NCOPY*512 f32]

typedef float f4 __attribute__((ext_vector_type(4)));

#define NCOPY 16

__global__ __launch_bounds__(256) void hist_kernel(
    const int* __restrict__ idx, int* __restrict__ counts, int n)
{
    int i = blockIdx.x * blockDim.x + threadIdx.x;
    const int stride = gridDim.x * blockDim.x;
    for (; i < n; i += stride) atomicAdd(&counts[idx[i]], 1);
}

__global__ __launch_bounds__(256) void scan_kernel(
    const int* __restrict__ counts,
    const float* __restrict__ memb,   // [V,256]
    const float* __restrict__ pre,    // [V,256]
    float* __restrict__ acc,          // [NCOPY][512]
    int vocab)
{
    const int lane = threadIdx.x & 63;
    const int wid  = (blockIdx.x * blockDim.x + threadIdx.x) >> 6;
    const int tab  = wid & 1;                 // 0 -> memb, 1 -> pre
    const int base = (wid >> 1) * 64;         // 64-row window per wave pair

    f4 a4 = {0.f, 0.f, 0.f, 0.f};

    if (base < vocab) {
        int c = 0;
        if (base + lane < vocab) c = counts[base + lane];   // coalesced
        const float cf = (float)c;
        unsigned long long m = __ballot(c != 0);

        const float* tbl = tab ? pre : memb;
        const f4* rows = reinterpret_cast<const f4*>(tbl) + (size_t)base * 64 + lane;

        // 4 surviving rows per iteration; all control flow is wave-uniform
        // (m is a ballot), deps are register-only -> 4x 1KB loads in flight.
        while (m) {
            const int k0 = __ffsll(m) - 1; m &= m - 1;
            const float w0 = __shfl(cf, k0, 64);
            int k1 = k0, k2 = k0, k3 = k0;
            float w1 = 0.f, w2 = 0.f, w3 = 0.f;
            if (m) { k1 = __ffsll(m) - 1; m &= m - 1; w1 = __shfl(cf, k1, 64); }
            if (m) { k2 = __ffsll(m) - 1; m &= m - 1; w2 = __shfl(cf, k2, 64); }
            if (m) { k3 = __ffsll(m) - 1; m &= m - 1; w3 = __shfl(cf, k3, 64); }

            const f4 a0 = rows[(size_t)k0 * 64];
            const f4 a1 = rows[(size_t)k1 * 64];
            const f4 a2 = rows[(size_t)k2 * 64];
            const f4 a3 = rows[(size_t)k3 * 64];

            a4 += a0 * w0;
            a4 += a1 * w1;
            a4 += a2 * w2;
            a4 += a3 * w3;
        }
    }

    // Block reduction: lane l of each wave owns channels [4l,4l+4);
    // even waves land in sAcc[0] (S), odd waves in sAcc[1] (P).
    __shared__ float sAcc[2][256];
    sAcc[0][threadIdx.x] = 0.f;
    sAcc[1][threadIdx.x] = 0.f;
    __syncthreads();

    const int ch = lane * 4;
    atomicAdd(&sAcc[tab][ch + 0], a4.x);
    atomicAdd(&sAcc[tab][ch + 1], a4.y);
    atomicAdd(&sAcc[tab][ch + 2], a4.z);
    atomicAdd(&sAcc[tab][ch + 3], a4.w);
    __syncthreads();

    float* myacc = acc + (size_t)(blockIdx.x & (NCOPY - 1)) * 512;
    atomicAdd(&myacc[threadIdx.x],       sAcc[0][threadIdx.x]);
    atomicAdd(&myacc[256 + threadIdx.x], sAcc[1][threadIdx.x]);
}

__global__ __launch_bounds__(256) void finish_kernel(
    const float* __restrict__ acc,    // [NCOPY][512]
    const float* __restrict__ W,      // [256,256] row-major
    const float* __restrict__ bias,
    float* __restrict__ out,          // [256]
    float nf)
{
    const int c = blockIdx.x;
    const int t = threadIdx.x;

    float s_t = 0.f;
    #pragma unroll
    for (int cp = 0; cp < NCOPY; ++cp) s_t += acc[cp * 512 + t];

    float v = W[(size_t)c * 256 + t] * s_t;
    for (int off = 32; off > 0; off >>= 1)
        v += __shfl_down(v, off, 64);

    __shared__ float part[4];
    if ((t & 63) == 0) part[t >> 6] = v;
    __syncthreads();

    if (t == 0) {
        float p_c = 0.f;
        #pragma unroll
        for (int cp = 0; cp < NCOPY; ++cp) p_c += acc[cp * 512 + 256 + c];
        out[c] = (part[0] + part[1] + part[2] + part[3]) + p_c + nf * bias[c];
    }
}

// Fallback (ws too small): direct strided gather into acc copies.
__global__ __launch_bounds__(256) void gather_sum_kernel(
    const int* __restrict__ idx,
    const float* __restrict__ memb,
    const float* __restrict__ pre,
    float* __restrict__ acc,
    int n)
{
    const int lane = threadIdx.x & 63;
    const int wave = threadIdx.x >> 6;
    const int globalWave = blockIdx.x * 4 + wave;
    const int totalWaves = gridDim.x * 4;

    f4 accS = {0.f,0.f,0.f,0.f};
    f4 accP = {0.f,0.f,0.f,0.f};

    for (int i = globalWave; i < n; i += totalWaves) {
        const int r = idx[i];
        const f4 a = reinterpret_cast<const f4*>(memb + (size_t)r * 256)[lane];
        const f4 b = reinterpret_cast<const f4*>(pre  + (size_t)r * 256)[lane];
        accS += a; accP += b;
    }

    __shared__ float sS[256];
    __shared__ float sP[256];
    sS[threadIdx.x] = 0.f;
    sP[threadIdx.x] = 0.f;
    __syncthreads();
    const int ch = lane * 4;
    atomicAdd(&sS[ch + 0], accS.x); atomicAdd(&sS[ch + 1], accS.y);
    atomicAdd(&sS[ch + 2], accS.z); atomicAdd(&sS[ch + 3], accS.w);
    atomicAdd(&sP[ch + 0], accP.x); atomicAdd(&sP[ch + 1], accP.y);
    atomicAdd(&sP[ch + 2], accP.z); atomicAdd(&sP[ch + 3], accP.w);
    __syncthreads();
    float* myacc = acc + (size_t)(blockIdx.x & (NCOPY - 1)) * 512;
    atomicAdd(&myacc[threadIdx.x],       sS[threadIdx.x]);
    atomicAdd(&myacc[256 + threadIdx.x], sP[threadIdx.x]);
}

extern "C" void kernel_launch(void* const* d_in, const int* in_sizes, int n_in,
                              void* d_out, int out_size, void* d_ws, size_t ws_size,
                              hipStream_t stream)
{
    const int*   idx  = (const int*)d_in[0];     // medicine_it      [N]
    const float* memb = (const float*)d_in[1];   // m_embeddings     [V,256]
    const float* pre  = (const float*)d_in[2];   // pretrained_weight[V,256]
    const float* W    = (const float*)d_in[3];   // W                [256,256]
    const float* bias = (const float*)d_in[4];   // bias             [256]
    float* out = (float*)d_out;

    const int n     = in_sizes[0];
    const int vocab = in_sizes[1] / 256;

    const size_t countsBytes = (size_t)vocab * sizeof(int);
    const size_t accBytes    = (size_t)NCOPY * 512 * sizeof(float);

    if (ws_size >= countsBytes + accBytes) {
        int*   counts = (int*)d_ws;
        float* acc    = (float*)((char*)d_ws + countsBytes);

        hipMemsetAsync(d_ws, 0, countsBytes + accBytes, stream);
        hist_kernel<<<400, 256, 0, stream>>>(idx, counts, n);

        const int waves  = 2 * ((vocab + 63) / 64);          // 6250
        const int blocks = (waves + 3) / 4;                  // 1563
        scan_kernel<<<blocks, 256, 0, stream>>>(counts, memb, pre, acc, vocab);
        finish_kernel<<<256, 256, 0, stream>>>(acc, W, bias, out, (float)n);
    } else {
        float* acc = (float*)d_ws;
        hipMemsetAsync(d_ws, 0, accBytes, stream);
        gather_sum_kernel<<<512, 256, 0, stream>>>(idx, memb, pre, acc, n);
        finish_kernel<<<256, 256, 0, stream>>>(acc, W, bias, out, (float)n);
    }
}